// Round 2
// baseline (10.790 us; speedup 1.0000x reference)
//
#include <hip/hip_runtime.h>

// CausalGraphGenerator: the reference's adjacency A is diagonal in (src,tgt):
//   A[b, src, tgt] = diag_vals[b, src] * eye[src, tgt]
// A diagonal matrix equals its own transpose, so A - A.transpose(0,2,1) == 0
// identically, for ANY input. Then relu(0 - h) = relu(-0.1) = 0, and the
// diagonal mask is a no-op on zeros. The reference output is exactly zero
// regardless of X/w1/b1/w2/b2. The entire conv/gelu/grad pipeline is dead
// code w.r.t. the output.
//
// Correct kernel = zero-fill d_out (4*64*64 = 16384 floats = 64 KiB).
// The harness poisons d_out to 0xAA before timing, so we must write zeros
// on every call.

__global__ void zero_fill_kernel(float* __restrict__ out, int n) {
    int i = blockIdx.x * blockDim.x + threadIdx.x;
    int n4 = n >> 2;  // number of whole float4s
    if (i < n4) {
        reinterpret_cast<float4*>(out)[i] = make_float4(0.f, 0.f, 0.f, 0.f);
    }
    // Scalar tail (dead for n = 16384, kept for generality): first <4 threads
    // of block 0 cover the remainder.
    if (blockIdx.x == 0) {
        int tail_start = n4 << 2;
        int j = tail_start + threadIdx.x;
        if (threadIdx.x < (n - tail_start)) out[j] = 0.f;
    }
}

extern "C" void kernel_launch(void* const* d_in, const int* in_sizes, int n_in,
                              void* d_out, int out_size, void* d_ws, size_t ws_size,
                              hipStream_t stream) {
    int n4 = out_size >> 2;                      // 4096 float4 stores
    int threads = 256;
    int blocks = (n4 + threads - 1) / threads;   // 16 blocks
    if (blocks < 1) blocks = 1;
    zero_fill_kernel<<<blocks, threads, 0, stream>>>((float*)d_out, out_size);
}